// Round 2
// baseline (569.417 us; speedup 1.0000x reference)
//
#include <hip/hip_runtime.h>

typedef unsigned short u16;
typedef __attribute__((ext_vector_type(8))) short short8;
typedef __attribute__((ext_vector_type(4))) float f32x4;

#define AS1 __attribute__((address_space(1)))
#define AS3 __attribute__((address_space(3)))

// Problem constants
constexpr int Bn = 4, Tn = 2048, Cn = 1024, Hn = 16, Dn = 64;
constexpr float SCL = 0.125f;                  // D^-0.5
constexpr float SCL_LOG2E = 0.125f * 1.44269504088896f; // fold into exp2 domain

__device__ __forceinline__ u16 f2bf(float f) {
  union { float f; unsigned u; } v; v.f = f;
  unsigned r = v.u + 0x7FFFu + ((v.u >> 16) & 1u);
  return (u16)(r >> 16);
}

__global__ void cast_f32_to_bf16(const float* __restrict__ in, u16* __restrict__ out, int n4) {
  int i = blockIdx.x * 256 + threadIdx.x;
  if (i >= n4) return;
  float4 v = ((const float4*)in)[i];
  ushort4 o;
  o.x = f2bf(v.x); o.y = f2bf(v.y); o.z = f2bf(v.z); o.w = f2bf(v.w);
  ((ushort4*)out)[i] = o;
}

__device__ __forceinline__ void store_out(u16* p, float v) { *p = f2bf(v); }
__device__ __forceinline__ void store_out(float* p, float v) { *p = v; }

// C[m,n] = sum_k A[m,k]*B[n,k] + bias[n]   (NT GEMM, bf16 in, f32 acc)
// 128x128 tile, BK=32, 256 threads (4 waves, each 64x64 = 4x4 frags of 16x16)
template <typename OT>
__global__ __launch_bounds__(256) void gemm_nt(
    const u16* __restrict__ A, const u16* __restrict__ Bm,
    const float* __restrict__ bias, OT* __restrict__ C,
    int M, int N, int K)
{
  __shared__ u16 As[128 * 32];
  __shared__ u16 Bs[128 * 32];
  const int tid = threadIdx.x;
  const int lane = tid & 63;
  const int wave = tid >> 6;
  const int m0 = blockIdx.y * 128;
  const int n0 = blockIdx.x * 128;
  const int wr = (wave >> 1) * 64;
  const int wc = (wave & 1) * 64;
  const int l15 = lane & 15;
  const int lg = lane >> 4;

  f32x4 acc[4][4] = {};

  for (int kt = 0; kt < K; kt += 32) {
#pragma unroll
    for (int it = 0; it < 2; ++it) {
      int c = it * 256 + tid;
      int row = c >> 2;
      int cc = c & 3;
      int cs = cc ^ ((row >> 1) & 3);
      const u16* ga = A + (m0 + row) * K + kt + cs * 8;
      __builtin_amdgcn_global_load_lds((const AS1 void*)ga, (AS3 void*)(As + c * 8), 16, 0, 0);
      const u16* gb = Bm + (n0 + row) * K + kt + cs * 8;
      __builtin_amdgcn_global_load_lds((const AS1 void*)gb, (AS3 void*)(Bs + c * 8), 16, 0, 0);
    }
    __syncthreads();

    short8 af[4], bfr[4];
#pragma unroll
    for (int i = 0; i < 4; ++i) {
      int rowa = wr + i * 16 + l15;
      int csa = lg ^ ((rowa >> 1) & 3);
      af[i] = *(const short8*)(As + (rowa * 32 + csa * 8));
      int rowb = wc + i * 16 + l15;
      int csb = lg ^ ((rowb >> 1) & 3);
      bfr[i] = *(const short8*)(Bs + (rowb * 32 + csb * 8));
    }
#pragma unroll
    for (int i = 0; i < 4; ++i)
#pragma unroll
      for (int j = 0; j < 4; ++j)
        acc[i][j] = __builtin_amdgcn_mfma_f32_16x16x32_bf16(af[i], bfr[j], acc[i][j], 0, 0, 0);
    __syncthreads();
  }

#pragma unroll
  for (int i = 0; i < 4; ++i) {
    int rowg = m0 + wr + i * 16 + lg * 4;
#pragma unroll
    for (int j = 0; j < 4; ++j) {
      int colg = n0 + wc + j * 16 + l15;
      float bv = bias[colg];
#pragma unroll
      for (int r = 0; r < 4; ++r)
        store_out(C + (size_t)(rowg + r) * N + colg, acc[i][j][r] + bv);
    }
  }
}

// Transpose V from qkv[B*T][3C] (v at +2C, per-head D=64) into vt[B,H,D,T].
// One block per (b,h, 64-row t-tile). 256 threads.
__global__ __launch_bounds__(256) void transpose_v(
    const u16* __restrict__ qkv, u16* __restrict__ vt)
{
  __shared__ u16 tile[64][72];  // +8 pad: conflict-free column writes / row reads
  const int bh = blockIdx.x >> 5;   // Tn/64 = 32 t-tiles
  const int tt = blockIdx.x & 31;
  const int b = bh >> 4;
  const int h = bh & 15;
  const int tid = threadIdx.x;
  const int trow = tid >> 2;        // 0..63
  const int dseg = tid & 3;         // 4 segs of 16 d

  const u16* src = qkv + (size_t)(b * Tn + tt * 64 + trow) * (3 * Cn) + 2 * Cn + h * Dn + dseg * 16;
  short8 v0 = *(const short8*)src;
  short8 v1 = *(const short8*)(src + 8);
#pragma unroll
  for (int e = 0; e < 8; ++e) {
    tile[dseg * 16 + e][trow] = (u16)v0[e];
    tile[dseg * 16 + 8 + e][trow] = (u16)v1[e];
  }
  __syncthreads();

  const int drow = tid >> 2;
  const int tseg = tid & 3;
  u16* dst = vt + (size_t)(bh * Dn + drow) * Tn + tt * 64 + tseg * 16;
  *(short8*)dst = *(const short8*)&tile[drow][tseg * 16];
  *(short8*)(dst + 8) = *(const short8*)&tile[drow][tseg * 16 + 8];
}

// Causal flash attention. 256 threads = 4 independent waves, 16 q-rows each
// (QBLK=64/block). KVBLK=64 per online-softmax update. V read from vt[B,H,D,T]
// (vectorized). Softmax in exp2 domain.
__global__ __launch_bounds__(256) void attn_kernel(
    const u16* __restrict__ qkv, const u16* __restrict__ vt, u16* __restrict__ att)
{
  __shared__ u16 p_lds[4][16 * 72];  // per-wave P tile, stride-72 pad
  const int tid = threadIdx.x;
  const int lane = tid & 63;
  const int w = tid >> 6;
  const int l15 = lane & 15;
  const int lg = lane >> 4;
  const int bh = blockIdx.x >> 5;   // Tn/64 = 32 q-tiles of 64
  const int qt = blockIdx.x & 31;
  const int b = bh >> 4;
  const int h = bh & 15;
  const int q0 = qt * 64 + w * 16;
  const int rowbase = b * Tn;
  const int koff = Cn + h * Dn;
  const size_t vbase = (size_t)bh * Dn * Tn;

  // Q fragments (A-layout): lane l: row=l&15, k(d) = kk*32 + lg*8 + e
  short8 qf0, qf1;
  {
    const u16* qp = qkv + (size_t)(rowbase + q0 + l15) * (3 * Cn) + h * Dn + lg * 8;
    qf0 = *(const short8*)qp;
    qf1 = *(const short8*)(qp + 32);
  }

  float m_r[4], l_r[4];
  f32x4 oacc[4] = {};
#pragma unroll
  for (int r = 0; r < 4; ++r) { m_r[r] = -1e30f; l_r[r] = 0.f; }

  u16* pw = p_lds[w];
  const int qlast = q0 + 15;

  for (int kt = 0; kt <= qlast; kt += 64) {
    // ---- S = Q K^T over 4 sub-tiles of 16 keys (exp2 domain) ----
    f32x4 e4[4];
    const bool need_mask = (kt + 63 > q0);
#pragma unroll
    for (int t = 0; t < 4; ++t) {
      const u16* kp = qkv + (size_t)(rowbase + kt + t * 16 + l15) * (3 * Cn) + koff + lg * 8;
      short8 kf0 = *(const short8*)kp;
      short8 kf1 = *(const short8*)(kp + 32);
      f32x4 z = {};
      z = __builtin_amdgcn_mfma_f32_16x16x32_bf16(qf0, kf0, z, 0, 0, 0);
      z = __builtin_amdgcn_mfma_f32_16x16x32_bf16(qf1, kf1, z, 0, 0, 0);
      if (need_mask) {
        int kcol = kt + t * 16 + l15;
#pragma unroll
        for (int r = 0; r < 4; ++r) {
          int qrow = q0 + lg * 4 + r;
          z[r] = (kcol > qrow) ? -1e30f : z[r] * SCL_LOG2E;
        }
      } else {
#pragma unroll
        for (int r = 0; r < 4; ++r) z[r] *= SCL_LOG2E;
      }
      e4[t] = z;
    }

    // ---- online softmax (rows live in 16-lane groups) ----
    float alpha[4];
#pragma unroll
    for (int r = 0; r < 4; ++r) {
      float mx = fmaxf(fmaxf(e4[0][r], e4[1][r]), fmaxf(e4[2][r], e4[3][r]));
      mx = fmaxf(mx, __shfl_xor(mx, 1));
      mx = fmaxf(mx, __shfl_xor(mx, 2));
      mx = fmaxf(mx, __shfl_xor(mx, 4));
      mx = fmaxf(mx, __shfl_xor(mx, 8));
      float mnew = fmaxf(m_r[r], mx);
      alpha[r] = __builtin_amdgcn_exp2f(m_r[r] - mnew);
      float ps = 0.f;
#pragma unroll
      for (int t = 0; t < 4; ++t) {
        float p = __builtin_amdgcn_exp2f(e4[t][r] - mnew);
        e4[t][r] = p;
        ps += p;
      }
      ps += __shfl_xor(ps, 1);
      ps += __shfl_xor(ps, 2);
      ps += __shfl_xor(ps, 4);
      ps += __shfl_xor(ps, 8);
      l_r[r] = l_r[r] * alpha[r] + ps;
      m_r[r] = mnew;
    }
#pragma unroll
    for (int j = 0; j < 4; ++j)
#pragma unroll
      for (int r = 0; r < 4; ++r)
        oacc[j][r] *= alpha[r];

    // ---- P: C-layout -> A-layout via per-wave LDS round trip (bf16) ----
#pragma unroll
    for (int t = 0; t < 4; ++t)
#pragma unroll
      for (int r = 0; r < 4; ++r)
        pw[(lg * 4 + r) * 72 + t * 16 + l15] = f2bf(e4[t][r]);
    asm volatile("s_waitcnt lgkmcnt(0)" ::: "memory");
    __builtin_amdgcn_sched_barrier(0);
    short8 pf[2];
    pf[0] = *(const short8*)(pw + l15 * 72 + lg * 8);
    pf[1] = *(const short8*)(pw + l15 * 72 + 32 + lg * 8);

    // ---- PV: out[16,64] += P[16,64] * V[64,64], V from vt (vectorized) ----
#pragma unroll
    for (int kk = 0; kk < 2; ++kk)
#pragma unroll
      for (int j = 0; j < 4; ++j) {
        short8 vf = *(const short8*)(vt + vbase + (size_t)(j * 16 + l15) * Tn + kt + kk * 32 + lg * 8);
        oacc[j] = __builtin_amdgcn_mfma_f32_16x16x32_bf16(pf[kk], vf, oacc[j], 0, 0, 0);
      }
  }

  // ---- epilogue ----
#pragma unroll
  for (int r = 0; r < 4; ++r) {
    float inv = __builtin_amdgcn_rcpf(l_r[r]);
#pragma unroll
    for (int j = 0; j < 4; ++j) {
      float v = oacc[j][r] * inv;
      att[(size_t)(rowbase + q0 + lg * 4 + r) * Cn + h * Dn + j * 16 + l15] = f2bf(v);
    }
  }
}

extern "C" void kernel_launch(void* const* d_in, const int* in_sizes, int n_in,
                              void* d_out, int out_size, void* d_ws, size_t ws_size,
                              hipStream_t stream) {
  const float* x      = (const float*)d_in[0];   // [B,T,C]
  const float* w_qkv  = (const float*)d_in[1];   // [3C,C]
  const float* b_qkv  = (const float*)d_in[2];   // [3C]
  const float* w_proj = (const float*)d_in[3];   // [C,C]
  const float* b_proj = (const float*)d_in[4];   // [C]
  float* out = (float*)d_out;                    // [B,T,C]

  char* ws = (char*)d_ws;
  u16* x_bf     = (u16*)(ws);                         // 16.78 MB (reused as vt)
  u16* wqkv_bf  = (u16*)(ws + 16777216);              //  6.29 MB
  u16* wproj_bf = (u16*)(ws + 16777216 + 6291456);    //  2.10 MB
  u16* qkv      = (u16*)(ws + 25165824);              // 50.33 MB
  u16* att      = (u16*)(ws + 75497472);              // 16.78 MB
  u16* vt       = x_bf;   // x_bf is dead after the QKV GEMM; reuse for V^T [B,H,D,T]

  const int M = Bn * Tn;  // 8192

  cast_f32_to_bf16<<<(M * Cn / 4 + 255) / 256, 256, 0, stream>>>(x, x_bf, M * Cn / 4);
  cast_f32_to_bf16<<<(3 * Cn * Cn / 4 + 255) / 256, 256, 0, stream>>>(w_qkv, wqkv_bf, 3 * Cn * Cn / 4);
  cast_f32_to_bf16<<<(Cn * Cn / 4 + 255) / 256, 256, 0, stream>>>(w_proj, wproj_bf, Cn * Cn / 4);

  // qkv = x @ w_qkv^T + b_qkv   [8192, 3072] bf16
  gemm_nt<u16><<<dim3(3 * Cn / 128, M / 128), 256, 0, stream>>>(
      x_bf, wqkv_bf, b_qkv, qkv, M, 3 * Cn, Cn);

  // V^T into vt[B,H,D,T]  (overwrites x_bf, now dead)
  transpose_v<<<Bn * Hn * (Tn / 64), 256, 0, stream>>>(qkv, vt);

  // causal flash attention -> att [8192, 1024] bf16
  attn_kernel<<<Bn * Hn * (Tn / 64), 256, 0, stream>>>(qkv, vt, att);

  // out = att @ w_proj^T + b_proj   [8192, 1024] f32
  gemm_nt<float><<<dim3(Cn / 128, M / 128), 256, 0, stream>>>(
      att, wproj_bf, b_proj, out, M, Cn, Cn);
}

// Round 3
// 267.289 us; speedup vs baseline: 2.1303x; 2.1303x over previous
//
#include <hip/hip_runtime.h>

typedef unsigned short u16;
typedef __attribute__((ext_vector_type(8))) short short8;
typedef __attribute__((ext_vector_type(4))) float f32x4;

#define AS1 __attribute__((address_space(1)))
#define AS3 __attribute__((address_space(3)))

// Problem constants
constexpr int Bn = 4, Tn = 2048, Cn = 1024, Hn = 16, Dn = 64;
constexpr float SCL_LOG2E = 0.125f * 1.44269504088896f; // D^-0.5 folded into exp2 domain

__device__ __forceinline__ u16 f2bf(float f) {
  union { float f; unsigned u; } v; v.f = f;
  unsigned r = v.u + 0x7FFFu + ((v.u >> 16) & 1u);
  return (u16)(r >> 16);
}

__global__ void cast_f32_to_bf16(const float* __restrict__ in, u16* __restrict__ out, int n4) {
  int i = blockIdx.x * 256 + threadIdx.x;
  if (i >= n4) return;
  float4 v = ((const float4*)in)[i];
  ushort4 o;
  o.x = f2bf(v.x); o.y = f2bf(v.y); o.z = f2bf(v.z); o.w = f2bf(v.w);
  ((ushort4*)out)[i] = o;
}

__device__ __forceinline__ void store_out(u16* p, float v) { *p = f2bf(v); }
__device__ __forceinline__ void store_out(float* p, float v) { *p = v; }

// C[m,n] = sum_k A[m,k]*B[n,k] + bias[n]   (NT GEMM, bf16 in, f32 acc)
template <typename OT>
__global__ __launch_bounds__(256) void gemm_nt(
    const u16* __restrict__ A, const u16* __restrict__ Bm,
    const float* __restrict__ bias, OT* __restrict__ C,
    int M, int N, int K)
{
  __shared__ u16 As[128 * 32];
  __shared__ u16 Bs[128 * 32];
  const int tid = threadIdx.x;
  const int lane = tid & 63;
  const int wave = tid >> 6;
  const int m0 = blockIdx.y * 128;
  const int n0 = blockIdx.x * 128;
  const int wr = (wave >> 1) * 64;
  const int wc = (wave & 1) * 64;
  const int l15 = lane & 15;
  const int lg = lane >> 4;

  f32x4 acc[4][4] = {};

  for (int kt = 0; kt < K; kt += 32) {
#pragma unroll
    for (int it = 0; it < 2; ++it) {
      int c = it * 256 + tid;
      int row = c >> 2;
      int cc = c & 3;
      int cs = cc ^ ((row >> 1) & 3);
      const u16* ga = A + (m0 + row) * K + kt + cs * 8;
      __builtin_amdgcn_global_load_lds((const AS1 void*)ga, (AS3 void*)(As + c * 8), 16, 0, 0);
      const u16* gb = Bm + (n0 + row) * K + kt + cs * 8;
      __builtin_amdgcn_global_load_lds((const AS1 void*)gb, (AS3 void*)(Bs + c * 8), 16, 0, 0);
    }
    __syncthreads();

    short8 af[4], bfr[4];
#pragma unroll
    for (int i = 0; i < 4; ++i) {
      int rowa = wr + i * 16 + l15;
      int csa = lg ^ ((rowa >> 1) & 3);
      af[i] = *(const short8*)(As + (rowa * 32 + csa * 8));
      int rowb = wc + i * 16 + l15;
      int csb = lg ^ ((rowb >> 1) & 3);
      bfr[i] = *(const short8*)(Bs + (rowb * 32 + csb * 8));
    }
#pragma unroll
    for (int i = 0; i < 4; ++i)
#pragma unroll
      for (int j = 0; j < 4; ++j)
        acc[i][j] = __builtin_amdgcn_mfma_f32_16x16x32_bf16(af[i], bfr[j], acc[i][j], 0, 0, 0);
    __syncthreads();
  }

#pragma unroll
  for (int i = 0; i < 4; ++i) {
    int rowg = m0 + wr + i * 16 + lg * 4;
#pragma unroll
    for (int j = 0; j < 4; ++j) {
      int colg = n0 + wc + j * 16 + l15;
      float bv = bias[colg];
#pragma unroll
      for (int r = 0; r < 4; ++r)
        store_out(C + (size_t)(rowg + r) * N + colg, acc[i][j][r] + bv);
    }
  }
}

// Transpose V from qkv[B*T][3C] (v at +2C, per-head D=64) into vt[B,H,D,T].
__global__ __launch_bounds__(256) void transpose_v(
    const u16* __restrict__ qkv, u16* __restrict__ vt)
{
  __shared__ u16 tile[64][72];
  const int bh = blockIdx.x >> 5;
  const int tt = blockIdx.x & 31;
  const int b = bh >> 4;
  const int h = bh & 15;
  const int tid = threadIdx.x;
  const int trow = tid >> 2;
  const int dseg = tid & 3;

  const u16* src = qkv + (size_t)(b * Tn + tt * 64 + trow) * (3 * Cn) + 2 * Cn + h * Dn + dseg * 16;
  short8 v0 = *(const short8*)src;
  short8 v1 = *(const short8*)(src + 8);
#pragma unroll
  for (int e = 0; e < 8; ++e) {
    tile[dseg * 16 + e][trow] = (u16)v0[e];
    tile[dseg * 16 + 8 + e][trow] = (u16)v1[e];
  }
  __syncthreads();

  const int drow = tid >> 2;
  const int tseg = tid & 3;
  u16* dst = vt + (size_t)(bh * Dn + drow) * Tn + tt * 64 + tseg * 16;
  *(short8*)dst = *(const short8*)&tile[drow][tseg * 16];
  *(short8*)(dst + 8) = *(const short8*)&tile[drow][tseg * 16 + 8];
}

// Causal flash attention, block = 4 waves, QBLK=128 (32 q-rows/wave), KVBLK=64.
// K and V^T staged once per block into double-buffered LDS (global_load_lds,
// XOR-swizzled src/read), prefetch-before-compute (T3 2-phase). Softmax exp2.
__global__ __launch_bounds__(256) void attn_kernel(
    const u16* __restrict__ qkv, const u16* __restrict__ vt, u16* __restrict__ att)
{
  __shared__ u16 Ks[2][64 * 64];
  __shared__ u16 Vs[2][64 * 64];
  __shared__ u16 Ps[4][32 * 64];
  const int tid = threadIdx.x;
  const int lane = tid & 63;
  const int w = tid >> 6;
  const int l15 = lane & 15;
  const int lg = lane >> 4;

  const int blk = blockIdx.x;
  const int qt = (Tn / 128 - 1) - (blk >> 6);   // heavy q-tiles dispatched first
  const int bh = blk & 63;
  const int b = bh >> 4;
  const int h = bh & 15;
  const int q0w = qt * 128 + w * 32;
  const int rowbase = b * Tn;
  const int koff = Cn + h * Dn;
  const size_t vbase = (size_t)bh * Dn * Tn;
  const int nt = 2 * qt + 2;                    // 64-wide k-tiles this block needs

  // Q fragments (A-layout): lane l: row=l&15, k(d) = kk*32 + lg*8 + e
  short8 qf[2][2];
#pragma unroll
  for (int i = 0; i < 2; ++i) {
    const u16* qp = qkv + (size_t)(rowbase + q0w + i * 16 + l15) * (3 * Cn) + h * Dn + lg * 8;
    qf[i][0] = *(const short8*)qp;
    qf[i][1] = *(const short8*)(qp + 32);
  }

  float m_r[2][4], l_r[2][4];
  f32x4 oacc[2][4] = {};
#pragma unroll
  for (int i = 0; i < 2; ++i)
#pragma unroll
    for (int r = 0; r < 4; ++r) { m_r[i][r] = -1e30f; l_r[i][r] = 0.f; }

  u16* pw = Ps[w];

  // Stage K-tile + V^T-tile `t` into buffer `buf`. LDS dest linear in lane
  // (global_load_lds requirement); source pre-swizzled chunk^=(row&7) so the
  // stride-128B fragment reads below are conflict-floor.
#define STAGE(buf, t_)                                                            \
  {                                                                               \
    const int kt_ = (t_) * 64;                                                    \
    _Pragma("unroll")                                                             \
    for (int it = 0; it < 2; ++it) {                                              \
      int c = it * 256 + tid;                                                     \
      int row = c >> 3;                                                           \
      int cs = (c & 7) ^ (row & 7);                                               \
      const u16* gk = qkv + (size_t)(rowbase + kt_ + row) * (3 * Cn) + koff + cs * 8; \
      __builtin_amdgcn_global_load_lds((const AS1 void*)gk, (AS3 void*)(&Ks[buf][c * 8]), 16, 0, 0); \
      const u16* gv = vt + vbase + (size_t)row * Tn + kt_ + cs * 8;               \
      __builtin_amdgcn_global_load_lds((const AS1 void*)gv, (AS3 void*)(&Vs[buf][c * 8]), 16, 0, 0); \
    }                                                                             \
  }

  STAGE(0, 0);
  __syncthreads();

  for (int t = 0; t < nt; ++t) {
    const int cur = t & 1;
    if (t + 1 < nt) STAGE(cur ^ 1, t + 1);      // prefetch overlaps compute
    const int kt = t * 64;
    const u16* Kb = Ks[cur];
    const u16* Vb = Vs[cur];

    // ---- S = Q K^T : 4 key sub-tiles x 2 q-row frags ----
    f32x4 s[2][4];
#pragma unroll
    for (int tt = 0; tt < 4; ++tt) {
      const int krow = tt * 16 + l15;
      short8 kf0 = *(const short8*)(Kb + krow * 64 + ((lg ^ (krow & 7)) << 3));
      short8 kf1 = *(const short8*)(Kb + krow * 64 + (((4 + lg) ^ (krow & 7)) << 3));
#pragma unroll
      for (int i = 0; i < 2; ++i) {
        f32x4 z = {};
        z = __builtin_amdgcn_mfma_f32_16x16x32_bf16(qf[i][0], kf0, z, 0, 0, 0);
        z = __builtin_amdgcn_mfma_f32_16x16x32_bf16(qf[i][1], kf1, z, 0, 0, 0);
        s[i][tt] = z;
      }
    }

    const bool need_mask = (kt + 63 > q0w);
#pragma unroll
    for (int i = 0; i < 2; ++i) {
      float alpha[4];
#pragma unroll
      for (int r = 0; r < 4; ++r) {
        const int qrow = q0w + i * 16 + lg * 4 + r;
        if (need_mask) {
#pragma unroll
          for (int tt = 0; tt < 4; ++tt) {
            int kcol = kt + tt * 16 + l15;
            s[i][tt][r] = (kcol > qrow) ? -1e30f : s[i][tt][r] * SCL_LOG2E;
          }
        } else {
#pragma unroll
          for (int tt = 0; tt < 4; ++tt) s[i][tt][r] *= SCL_LOG2E;
        }
        float mx = fmaxf(fmaxf(s[i][0][r], s[i][1][r]), fmaxf(s[i][2][r], s[i][3][r]));
        mx = fmaxf(mx, __shfl_xor(mx, 1));
        mx = fmaxf(mx, __shfl_xor(mx, 2));
        mx = fmaxf(mx, __shfl_xor(mx, 4));
        mx = fmaxf(mx, __shfl_xor(mx, 8));
        const float mnew = fmaxf(m_r[i][r], mx);
        alpha[r] = __builtin_amdgcn_exp2f(m_r[i][r] - mnew);
        float ps = 0.f;
#pragma unroll
        for (int tt = 0; tt < 4; ++tt) {
          float p = __builtin_amdgcn_exp2f(s[i][tt][r] - mnew);
          s[i][tt][r] = p;
          ps += p;
        }
        ps += __shfl_xor(ps, 1);
        ps += __shfl_xor(ps, 2);
        ps += __shfl_xor(ps, 4);
        ps += __shfl_xor(ps, 8);
        l_r[i][r] = l_r[i][r] * alpha[r] + ps;
        m_r[i][r] = mnew;
      }
#pragma unroll
      for (int j = 0; j < 4; ++j)
#pragma unroll
        for (int r = 0; r < 4; ++r)
          oacc[i][j][r] *= alpha[r];

      // P: C-layout -> A-layout via per-wave LDS (swizzled, stride 64)
#pragma unroll
      for (int tt = 0; tt < 4; ++tt)
#pragma unroll
        for (int r = 0; r < 4; ++r) {
          const int prow = i * 16 + lg * 4 + r;
          const int cs = (2 * tt + (l15 >> 3)) ^ (prow & 7);
          pw[prow * 64 + cs * 8 + (l15 & 7)] = f2bf(s[i][tt][r]);
        }
    }
    asm volatile("s_waitcnt lgkmcnt(0)" ::: "memory");
    __builtin_amdgcn_sched_barrier(0);

    short8 pf[2][2];
#pragma unroll
    for (int i = 0; i < 2; ++i) {
      const int prow = i * 16 + l15;
      pf[i][0] = *(const short8*)(pw + prow * 64 + (((lg) ^ (prow & 7)) << 3));
      pf[i][1] = *(const short8*)(pw + prow * 64 + (((4 + lg) ^ (prow & 7)) << 3));
    }

    // ---- PV: oacc[32,64] += P[32,64] * V[64,64] (V^T rows from LDS) ----
#pragma unroll
    for (int j = 0; j < 4; ++j) {
      const int vrow = j * 16 + l15;
      short8 vf0 = *(const short8*)(Vb + vrow * 64 + ((lg ^ (vrow & 7)) << 3));
      short8 vf1 = *(const short8*)(Vb + vrow * 64 + (((4 + lg) ^ (vrow & 7)) << 3));
#pragma unroll
      for (int i = 0; i < 2; ++i) {
        oacc[i][j] = __builtin_amdgcn_mfma_f32_16x16x32_bf16(pf[i][0], vf0, oacc[i][j], 0, 0, 0);
        oacc[i][j] = __builtin_amdgcn_mfma_f32_16x16x32_bf16(pf[i][1], vf1, oacc[i][j], 0, 0, 0);
      }
    }
    __syncthreads();   // drains prefetch (vmcnt) + all waves done with `cur`
  }

  // ---- epilogue ----
#pragma unroll
  for (int i = 0; i < 2; ++i)
#pragma unroll
    for (int r = 0; r < 4; ++r) {
      float inv = __builtin_amdgcn_rcpf(l_r[i][r]);
      const int grow = rowbase + q0w + i * 16 + lg * 4 + r;
#pragma unroll
      for (int j = 0; j < 4; ++j)
        att[(size_t)grow * Cn + h * Dn + j * 16 + l15] = f2bf(oacc[i][j][r] * inv);
    }
#undef STAGE
}

extern "C" void kernel_launch(void* const* d_in, const int* in_sizes, int n_in,
                              void* d_out, int out_size, void* d_ws, size_t ws_size,
                              hipStream_t stream) {
  const float* x      = (const float*)d_in[0];   // [B,T,C]
  const float* w_qkv  = (const float*)d_in[1];   // [3C,C]
  const float* b_qkv  = (const float*)d_in[2];   // [3C]
  const float* w_proj = (const float*)d_in[3];   // [C,C]
  const float* b_proj = (const float*)d_in[4];   // [C]
  float* out = (float*)d_out;                    // [B,T,C]

  char* ws = (char*)d_ws;
  u16* x_bf     = (u16*)(ws);                         // 16.78 MB (reused as vt)
  u16* wqkv_bf  = (u16*)(ws + 16777216);              //  6.29 MB
  u16* wproj_bf = (u16*)(ws + 16777216 + 6291456);    //  2.10 MB
  u16* qkv      = (u16*)(ws + 25165824);              // 50.33 MB
  u16* att      = (u16*)(ws + 75497472);              // 16.78 MB
  u16* vt       = x_bf;   // x_bf dead after QKV GEMM; reuse for V^T [B,H,D,T]

  const int M = Bn * Tn;  // 8192

  cast_f32_to_bf16<<<(M * Cn / 4 + 255) / 256, 256, 0, stream>>>(x, x_bf, M * Cn / 4);
  cast_f32_to_bf16<<<(3 * Cn * Cn / 4 + 255) / 256, 256, 0, stream>>>(w_qkv, wqkv_bf, 3 * Cn * Cn / 4);
  cast_f32_to_bf16<<<(Cn * Cn / 4 + 255) / 256, 256, 0, stream>>>(w_proj, wproj_bf, Cn * Cn / 4);

  // qkv = x @ w_qkv^T + b_qkv   [8192, 3072] bf16
  gemm_nt<u16><<<dim3(3 * Cn / 128, M / 128), 256, 0, stream>>>(
      x_bf, wqkv_bf, b_qkv, qkv, M, 3 * Cn, Cn);

  // V^T into vt[B,H,D,T]  (overwrites x_bf, now dead)
  transpose_v<<<Bn * Hn * (Tn / 64), 256, 0, stream>>>(qkv, vt);

  // causal flash attention -> att [8192, 1024] bf16
  attn_kernel<<<Bn * Hn * (Tn / 128), 256, 0, stream>>>(qkv, vt, att);

  // out = att @ w_proj^T + b_proj   [8192, 1024] f32
  gemm_nt<float><<<dim3(Cn / 128, M / 128), 256, 0, stream>>>(
      att, wproj_bf, b_proj, out, M, Cn, Cn);
}

// Round 4
// 239.506 us; speedup vs baseline: 2.3775x; 1.1160x over previous
//
#include <hip/hip_runtime.h>

typedef unsigned short u16;
typedef __attribute__((ext_vector_type(8))) short short8;
typedef __attribute__((ext_vector_type(4))) float f32x4;

#define AS1 __attribute__((address_space(1)))
#define AS3 __attribute__((address_space(3)))

// Problem constants
constexpr int Bn = 4, Tn = 2048, Cn = 1024, Hn = 16, Dn = 64;
constexpr float SCL_LOG2E = 0.125f * 1.44269504088896f; // D^-0.5 folded into exp2 domain

__device__ __forceinline__ u16 f2bf(float f) {
  union { float f; unsigned u; } v; v.f = f;
  unsigned r = v.u + 0x7FFFu + ((v.u >> 16) & 1u);
  return (u16)(r >> 16);
}

__global__ void cast_f32_to_bf16(const float* __restrict__ in, u16* __restrict__ out, int n4) {
  int i = blockIdx.x * 256 + threadIdx.x;
  if (i >= n4) return;
  float4 v = ((const float4*)in)[i];
  ushort4 o;
  o.x = f2bf(v.x); o.y = f2bf(v.y); o.z = f2bf(v.z); o.w = f2bf(v.w);
  ((ushort4*)out)[i] = o;
}

__device__ __forceinline__ void store_out(u16* p, float v) { *p = f2bf(v); }
__device__ __forceinline__ void store_out(float* p, float v) { *p = v; }

// C[m,n] = (sum_k A[m,k]*B[n,k] + bias[n]) * (n < qcols ? qscale : 1)
template <typename OT>
__global__ __launch_bounds__(256) void gemm_nt(
    const u16* __restrict__ A, const u16* __restrict__ Bm,
    const float* __restrict__ bias, OT* __restrict__ C,
    int M, int N, int K, int qcols, float qscale)
{
  __shared__ u16 As[128 * 32];
  __shared__ u16 Bs[128 * 32];
  const int tid = threadIdx.x;
  const int lane = tid & 63;
  const int wave = tid >> 6;
  const int m0 = blockIdx.y * 128;
  const int n0 = blockIdx.x * 128;
  const int wr = (wave >> 1) * 64;
  const int wc = (wave & 1) * 64;
  const int l15 = lane & 15;
  const int lg = lane >> 4;

  f32x4 acc[4][4] = {};

  for (int kt = 0; kt < K; kt += 32) {
#pragma unroll
    for (int it = 0; it < 2; ++it) {
      int c = it * 256 + tid;
      int row = c >> 2;
      int cc = c & 3;
      int cs = cc ^ ((row >> 1) & 3);
      const u16* ga = A + (m0 + row) * K + kt + cs * 8;
      __builtin_amdgcn_global_load_lds((const AS1 void*)ga, (AS3 void*)(As + c * 8), 16, 0, 0);
      const u16* gb = Bm + (n0 + row) * K + kt + cs * 8;
      __builtin_amdgcn_global_load_lds((const AS1 void*)gb, (AS3 void*)(Bs + c * 8), 16, 0, 0);
    }
    __syncthreads();

    short8 af[4], bfr[4];
#pragma unroll
    for (int i = 0; i < 4; ++i) {
      int rowa = wr + i * 16 + l15;
      int csa = lg ^ ((rowa >> 1) & 3);
      af[i] = *(const short8*)(As + (rowa * 32 + csa * 8));
      int rowb = wc + i * 16 + l15;
      int csb = lg ^ ((rowb >> 1) & 3);
      bfr[i] = *(const short8*)(Bs + (rowb * 32 + csb * 8));
    }
#pragma unroll
    for (int i = 0; i < 4; ++i)
#pragma unroll
      for (int j = 0; j < 4; ++j)
        acc[i][j] = __builtin_amdgcn_mfma_f32_16x16x32_bf16(af[i], bfr[j], acc[i][j], 0, 0, 0);
    __syncthreads();
  }

#pragma unroll
  for (int i = 0; i < 4; ++i) {
    int rowg = m0 + wr + i * 16 + lg * 4;
#pragma unroll
    for (int j = 0; j < 4; ++j) {
      int colg = n0 + wc + j * 16 + l15;
      float sc = (colg < qcols) ? qscale : 1.0f;
      float bv = bias[colg];
#pragma unroll
      for (int r = 0; r < 4; ++r)
        store_out(C + (size_t)(rowg + r) * N + colg, (acc[i][j][r] + bv) * sc);
    }
  }
}

// Transpose V from qkv[B*T][3C] (v at +2C, per-head D=64) into vt[B,H,D,T].
__global__ __launch_bounds__(256) void transpose_v(
    const u16* __restrict__ qkv, u16* __restrict__ vt)
{
  __shared__ u16 tile[64][72];
  const int bh = blockIdx.x >> 5;
  const int tt = blockIdx.x & 31;
  const int b = bh >> 4;
  const int h = bh & 15;
  const int tid = threadIdx.x;
  const int trow = tid >> 2;
  const int dseg = tid & 3;

  const u16* src = qkv + (size_t)(b * Tn + tt * 64 + trow) * (3 * Cn) + 2 * Cn + h * Dn + dseg * 16;
  short8 v0 = *(const short8*)src;
  short8 v1 = *(const short8*)(src + 8);
#pragma unroll
  for (int e = 0; e < 8; ++e) {
    tile[dseg * 16 + e][trow] = (u16)v0[e];
    tile[dseg * 16 + 8 + e][trow] = (u16)v1[e];
  }
  __syncthreads();

  const int drow = tid >> 2;
  const int tseg = tid & 3;
  u16* dst = vt + (size_t)(bh * Dn + drow) * Tn + tt * 64 + tseg * 16;
  *(short8*)dst = *(const short8*)&tile[drow][tseg * 16];
  *(short8*)(dst + 8) = *(const short8*)&tile[drow][tseg * 16 + 8];
}

// Causal flash attention, block = 4 waves, QBLK=128 (32 q-rows/wave), KVBLK=64.
// K and V^T staged per block into double-buffered LDS; prefetch-before-compute.
// Q pre-scaled by SCL*log2e in the QKV GEMM -> scores already in exp2 domain.
// Defer-max (THR=8 log2): skip alpha-rescale unless the running max grew.
__global__ __launch_bounds__(256) void attn_kernel(
    const u16* __restrict__ qkv, const u16* __restrict__ vt, u16* __restrict__ att)
{
  __shared__ u16 Ks[2][64 * 64];
  __shared__ u16 Vs[2][64 * 64];
  __shared__ u16 Ps[4][32 * 64];
  const int tid = threadIdx.x;
  const int lane = tid & 63;
  const int w = tid >> 6;
  const int l15 = lane & 15;
  const int lg = lane >> 4;

  const int blk = blockIdx.x;
  const int qt = (Tn / 128 - 1) - (blk >> 6);   // heavy q-tiles dispatched first
  const int bh = blk & 63;
  const int b = bh >> 4;
  const int h = bh & 15;
  const int q0w = qt * 128 + w * 32;
  const int rowbase = b * Tn;
  const int koff = Cn + h * Dn;
  const size_t vbase = (size_t)bh * Dn * Tn;
  const int nt = 2 * qt + 2;                    // 64-wide k-tiles staged by block
  const int ntw = 2 * qt + 1 + (w >> 1);        // tiles this wave actually computes

  short8 qf[2][2];
#pragma unroll
  for (int i = 0; i < 2; ++i) {
    const u16* qp = qkv + (size_t)(rowbase + q0w + i * 16 + l15) * (3 * Cn) + h * Dn + lg * 8;
    qf[i][0] = *(const short8*)qp;
    qf[i][1] = *(const short8*)(qp + 32);
  }

  float m_r[2][4], l_r[2][4];
  f32x4 oacc[2][4] = {};
#pragma unroll
  for (int i = 0; i < 2; ++i)
#pragma unroll
    for (int r = 0; r < 4; ++r) { m_r[i][r] = -1e30f; l_r[i][r] = 0.f; }

  u16* pw = Ps[w];

#define STAGE(buf, t_)                                                            \
  {                                                                               \
    const int kt_ = (t_) * 64;                                                    \
    _Pragma("unroll")                                                             \
    for (int it = 0; it < 2; ++it) {                                              \
      int c = it * 256 + tid;                                                     \
      int row = c >> 3;                                                           \
      int cs = (c & 7) ^ (row & 7);                                               \
      const u16* gk = qkv + (size_t)(rowbase + kt_ + row) * (3 * Cn) + koff + cs * 8; \
      __builtin_amdgcn_global_load_lds((const AS1 void*)gk, (AS3 void*)(&Ks[buf][c * 8]), 16, 0, 0); \
      const u16* gv = vt + vbase + (size_t)row * Tn + kt_ + cs * 8;               \
      __builtin_amdgcn_global_load_lds((const AS1 void*)gv, (AS3 void*)(&Vs[buf][c * 8]), 16, 0, 0); \
    }                                                                             \
  }

  STAGE(0, 0);
  __syncthreads();

  for (int t = 0; t < nt; ++t) {
    const int cur = t & 1;
    if (t + 1 < nt) STAGE(cur ^ 1, t + 1);      // prefetch overlaps compute
    if (t < ntw) {
      const int kt = t * 64;
      const u16* Kb = Ks[cur];
      const u16* Vb = Vs[cur];

      // ---- S = Q K^T : 4 key sub-tiles x 2 q-row frags (already exp2-domain) ----
      f32x4 s[2][4];
#pragma unroll
      for (int tt = 0; tt < 4; ++tt) {
        const int krow = tt * 16 + l15;
        short8 kf0 = *(const short8*)(Kb + krow * 64 + ((lg ^ (krow & 7)) << 3));
        short8 kf1 = *(const short8*)(Kb + krow * 64 + (((4 + lg) ^ (krow & 7)) << 3));
#pragma unroll
        for (int i = 0; i < 2; ++i) {
          f32x4 z = {};
          z = __builtin_amdgcn_mfma_f32_16x16x32_bf16(qf[i][0], kf0, z, 0, 0, 0);
          z = __builtin_amdgcn_mfma_f32_16x16x32_bf16(qf[i][1], kf1, z, 0, 0, 0);
          s[i][tt] = z;
        }
      }

      const bool need_mask = (kt + 63 > q0w);
#pragma unroll
      for (int i = 0; i < 2; ++i) {
        if (need_mask) {
#pragma unroll
          for (int r = 0; r < 4; ++r) {
            const int qrow = q0w + i * 16 + lg * 4 + r;
#pragma unroll
            for (int tt = 0; tt < 4; ++tt) {
              int kcol = kt + tt * 16 + l15;
              if (kcol > qrow) s[i][tt][r] = -1e30f;
            }
          }
        }
        // row maxes + defer-max decision
        float mx[4];
        bool resc = false;
#pragma unroll
        for (int r = 0; r < 4; ++r) {
          float m0 = fmaxf(fmaxf(s[i][0][r], s[i][1][r]), fmaxf(s[i][2][r], s[i][3][r]));
          m0 = fmaxf(m0, __shfl_xor(m0, 1));
          m0 = fmaxf(m0, __shfl_xor(m0, 2));
          m0 = fmaxf(m0, __shfl_xor(m0, 4));
          m0 = fmaxf(m0, __shfl_xor(m0, 8));
          mx[r] = m0;
          resc |= (m0 > m_r[i][r] + 8.f);
        }
        if (__any(resc)) {
#pragma unroll
          for (int r = 0; r < 4; ++r) {
            float mnew = fmaxf(m_r[i][r], mx[r]);
            float a = __builtin_amdgcn_exp2f(m_r[i][r] - mnew);
            m_r[i][r] = mnew;
            l_r[i][r] *= a;
#pragma unroll
            for (int j = 0; j < 4; ++j) oacc[i][j][r] *= a;
          }
        }
#pragma unroll
        for (int r = 0; r < 4; ++r) {
          float ps = 0.f;
#pragma unroll
          for (int tt = 0; tt < 4; ++tt) {
            float p = __builtin_amdgcn_exp2f(s[i][tt][r] - m_r[i][r]);
            s[i][tt][r] = p;
            ps += p;
          }
          ps += __shfl_xor(ps, 1);
          ps += __shfl_xor(ps, 2);
          ps += __shfl_xor(ps, 4);
          ps += __shfl_xor(ps, 8);
          l_r[i][r] += ps;
        }

        // P: C-layout -> A-layout via per-wave LDS (swizzled, stride 64)
#pragma unroll
        for (int tt = 0; tt < 4; ++tt)
#pragma unroll
          for (int r = 0; r < 4; ++r) {
            const int prow = i * 16 + lg * 4 + r;
            const int cs = (2 * tt + (l15 >> 3)) ^ (prow & 7);
            pw[prow * 64 + cs * 8 + (l15 & 7)] = f2bf(s[i][tt][r]);
          }
      }
      asm volatile("s_waitcnt lgkmcnt(0)" ::: "memory");
      __builtin_amdgcn_sched_barrier(0);

      short8 pf[2][2];
#pragma unroll
      for (int i = 0; i < 2; ++i) {
        const int prow = i * 16 + l15;
        pf[i][0] = *(const short8*)(pw + prow * 64 + (((lg) ^ (prow & 7)) << 3));
        pf[i][1] = *(const short8*)(pw + prow * 64 + (((4 + lg) ^ (prow & 7)) << 3));
      }

      // ---- PV: oacc[32,64] += P[32,64] * V[64,64] ----
#pragma unroll
      for (int j = 0; j < 4; ++j) {
        const int vrow = j * 16 + l15;
        short8 vf0 = *(const short8*)(Vb + vrow * 64 + ((lg ^ (vrow & 7)) << 3));
        short8 vf1 = *(const short8*)(Vb + vrow * 64 + (((4 + lg) ^ (vrow & 7)) << 3));
#pragma unroll
        for (int i = 0; i < 2; ++i) {
          oacc[i][j] = __builtin_amdgcn_mfma_f32_16x16x32_bf16(pf[i][0], vf0, oacc[i][j], 0, 0, 0);
          oacc[i][j] = __builtin_amdgcn_mfma_f32_16x16x32_bf16(pf[i][1], vf1, oacc[i][j], 0, 0, 0);
        }
      }
    }
    __syncthreads();   // drains prefetch (vmcnt) + all waves done with `cur`
  }

  // ---- epilogue ----
#pragma unroll
  for (int i = 0; i < 2; ++i)
#pragma unroll
    for (int r = 0; r < 4; ++r) {
      float inv = __builtin_amdgcn_rcpf(l_r[i][r]);
      const int grow = rowbase + q0w + i * 16 + lg * 4 + r;
#pragma unroll
      for (int j = 0; j < 4; ++j)
        att[(size_t)grow * Cn + h * Dn + j * 16 + l15] = f2bf(oacc[i][j][r] * inv);
    }
#undef STAGE
}

extern "C" void kernel_launch(void* const* d_in, const int* in_sizes, int n_in,
                              void* d_out, int out_size, void* d_ws, size_t ws_size,
                              hipStream_t stream) {
  const float* x      = (const float*)d_in[0];   // [B,T,C]
  const float* w_qkv  = (const float*)d_in[1];   // [3C,C]
  const float* b_qkv  = (const float*)d_in[2];   // [3C]
  const float* w_proj = (const float*)d_in[3];   // [C,C]
  const float* b_proj = (const float*)d_in[4];   // [C]
  float* out = (float*)d_out;                    // [B,T,C]

  char* ws = (char*)d_ws;
  u16* x_bf     = (u16*)(ws);                         // 16.78 MB (reused as vt)
  u16* wqkv_bf  = (u16*)(ws + 16777216);              //  6.29 MB
  u16* wproj_bf = (u16*)(ws + 16777216 + 6291456);    //  2.10 MB
  u16* qkv      = (u16*)(ws + 25165824);              // 50.33 MB
  u16* att      = (u16*)(ws + 75497472);              // 16.78 MB
  u16* vt       = x_bf;   // x_bf dead after QKV GEMM; reuse for V^T [B,H,D,T]

  const int M = Bn * Tn;  // 8192

  cast_f32_to_bf16<<<(M * Cn / 4 + 255) / 256, 256, 0, stream>>>(x, x_bf, M * Cn / 4);
  cast_f32_to_bf16<<<(3 * Cn * Cn / 4 + 255) / 256, 256, 0, stream>>>(w_qkv, wqkv_bf, 3 * Cn * Cn / 4);
  cast_f32_to_bf16<<<(Cn * Cn / 4 + 255) / 256, 256, 0, stream>>>(w_proj, wproj_bf, Cn * Cn / 4);

  // qkv = x @ w_qkv^T + b_qkv; Q region (cols < 1024) pre-scaled by SCL*log2e
  gemm_nt<u16><<<dim3(3 * Cn / 128, M / 128), 256, 0, stream>>>(
      x_bf, wqkv_bf, b_qkv, qkv, M, 3 * Cn, Cn, Cn, SCL_LOG2E);

  // V^T into vt[B,H,D,T]  (overwrites x_bf, now dead)
  transpose_v<<<Bn * Hn * (Tn / 64), 256, 0, stream>>>(qkv, vt);

  // causal flash attention -> att [8192, 1024] bf16
  attn_kernel<<<Bn * Hn * (Tn / 128), 256, 0, stream>>>(qkv, vt, att);

  // out = att @ w_proj^T + b_proj   [8192, 1024] f32
  gemm_nt<float><<<dim3(Cn / 128, M / 128), 256, 0, stream>>>(
      att, wproj_bf, b_proj, out, M, Cn, Cn, 0, 1.0f);
}

// Round 5
// 185.353 us; speedup vs baseline: 3.0721x; 1.2922x over previous
//
#include <hip/hip_runtime.h>

typedef unsigned short u16;
typedef __attribute__((ext_vector_type(8))) short short8;
typedef __attribute__((ext_vector_type(4))) float f32x4;
typedef __attribute__((ext_vector_type(16))) float f32x16;
typedef __attribute__((ext_vector_type(2))) unsigned uint2v;
typedef __attribute__((ext_vector_type(4))) unsigned u32x4;

#define AS1 __attribute__((address_space(1)))
#define AS3 __attribute__((address_space(3)))

// Problem constants
constexpr int Bn = 4, Tn = 2048, Cn = 1024, Hn = 16, Dn = 64;
constexpr float SCL_LOG2E = 0.125f * 1.44269504088896f; // D^-0.5 folded into exp2 domain

__device__ __forceinline__ u16 f2bf(float f) {
  union { float f; unsigned u; } v; v.f = f;
  unsigned r = v.u + 0x7FFFu + ((v.u >> 16) & 1u);
  return (u16)(r >> 16);
}

__device__ __forceinline__ unsigned cvtpk_bf16(float a, float b) {
  unsigned r;
  asm("v_cvt_pk_bf16_f32 %0, %1, %2" : "=v"(r) : "v"(a), "v"(b));
  return r;
}

__global__ void cast_f32_to_bf16(const float* __restrict__ in, u16* __restrict__ out, int n4) {
  int i = blockIdx.x * 256 + threadIdx.x;
  if (i >= n4) return;
  float4 v = ((const float4*)in)[i];
  ushort4 o;
  o.x = f2bf(v.x); o.y = f2bf(v.y); o.z = f2bf(v.z); o.w = f2bf(v.w);
  ((ushort4*)out)[i] = o;
}

__device__ __forceinline__ void store_out(u16* p, float v) { *p = f2bf(v); }
__device__ __forceinline__ void store_out(float* p, float v) { *p = v; }

// C[m,n] = (sum_k A[m,k]*B[n,k] + bias[n]) * (n < qcols ? qscale : 1)
template <typename OT>
__global__ __launch_bounds__(256) void gemm_nt(
    const u16* __restrict__ A, const u16* __restrict__ Bm,
    const float* __restrict__ bias, OT* __restrict__ C,
    int M, int N, int K, int qcols, float qscale)
{
  __shared__ u16 As[128 * 32];
  __shared__ u16 Bs[128 * 32];
  const int tid = threadIdx.x;
  const int lane = tid & 63;
  const int wave = tid >> 6;
  const int m0 = blockIdx.y * 128;
  const int n0 = blockIdx.x * 128;
  const int wr = (wave >> 1) * 64;
  const int wc = (wave & 1) * 64;
  const int l15 = lane & 15;
  const int lg = lane >> 4;

  f32x4 acc[4][4] = {};

  for (int kt = 0; kt < K; kt += 32) {
#pragma unroll
    for (int it = 0; it < 2; ++it) {
      int c = it * 256 + tid;
      int row = c >> 2;
      int cc = c & 3;
      int cs = cc ^ ((row >> 1) & 3);
      const u16* ga = A + (m0 + row) * K + kt + cs * 8;
      __builtin_amdgcn_global_load_lds((const AS1 void*)ga, (AS3 void*)(As + c * 8), 16, 0, 0);
      const u16* gb = Bm + (n0 + row) * K + kt + cs * 8;
      __builtin_amdgcn_global_load_lds((const AS1 void*)gb, (AS3 void*)(Bs + c * 8), 16, 0, 0);
    }
    __syncthreads();

    short8 af[4], bfr[4];
#pragma unroll
    for (int i = 0; i < 4; ++i) {
      int rowa = wr + i * 16 + l15;
      int csa = lg ^ ((rowa >> 1) & 3);
      af[i] = *(const short8*)(As + (rowa * 32 + csa * 8));
      int rowb = wc + i * 16 + l15;
      int csb = lg ^ ((rowb >> 1) & 3);
      bfr[i] = *(const short8*)(Bs + (rowb * 32 + csb * 8));
    }
#pragma unroll
    for (int i = 0; i < 4; ++i)
#pragma unroll
      for (int j = 0; j < 4; ++j)
        acc[i][j] = __builtin_amdgcn_mfma_f32_16x16x32_bf16(af[i], bfr[j], acc[i][j], 0, 0, 0);
    __syncthreads();
  }

#pragma unroll
  for (int i = 0; i < 4; ++i) {
    int rowg = m0 + wr + i * 16 + lg * 4;
#pragma unroll
    for (int j = 0; j < 4; ++j) {
      int colg = n0 + wc + j * 16 + l15;
      float sc = (colg < qcols) ? qscale : 1.0f;
      float bv = bias[colg];
#pragma unroll
      for (int r = 0; r < 4; ++r)
        store_out(C + (size_t)(rowg + r) * N + colg, (acc[i][j][r] + bv) * sc);
    }
  }
}

// Transpose V from qkv[B*T][3C] (v at +2C, per-head D=64) into vt[B,H,D,T].
__global__ __launch_bounds__(256) void transpose_v(
    const u16* __restrict__ qkv, u16* __restrict__ vt)
{
  __shared__ u16 tile[64][72];
  const int bh = blockIdx.x >> 5;
  const int tt = blockIdx.x & 31;
  const int b = bh >> 4;
  const int h = bh & 15;
  const int tid = threadIdx.x;
  const int trow = tid >> 2;
  const int dseg = tid & 3;

  const u16* src = qkv + (size_t)(b * Tn + tt * 64 + trow) * (3 * Cn) + 2 * Cn + h * Dn + dseg * 16;
  short8 v0 = *(const short8*)src;
  short8 v1 = *(const short8*)(src + 8);
#pragma unroll
  for (int e = 0; e < 8; ++e) {
    tile[dseg * 16 + e][trow] = (u16)v0[e];
    tile[dseg * 16 + 8 + e][trow] = (u16)v1[e];
  }
  __syncthreads();

  const int drow = tid >> 2;
  const int tseg = tid & 3;
  u16* dst = vt + (size_t)(bh * Dn + drow) * Tn + tt * 64 + tseg * 16;
  *(short8*)dst = *(const short8*)&tile[drow][tseg * 16];
  *(short8*)(dst + 8) = *(const short8*)&tile[drow][tseg * 16 + 8];
}

// Causal flash attention, swapped-operand structure (m214 style):
//   S^T = mfma_32x32x16(A=K, B=Q)  -> lane owns full q-row (q = lane&31)
//   softmax fully in-lane (31 VALU + 1 shfl per reduce)
//   P -> bf16 B-frags via v_cvt_pk_bf16_f32 + v_permlane32_swap_b32 (T12)
//   O^T = mfma(A=V^T-frag, B=P-frag) -> O, m, l all lane-local
// Block = 4 waves x 32 q-rows = QBLK 128; KVBLK=64, double-buffered LDS staging.
__global__ __launch_bounds__(256) void attn_kernel(
    const u16* __restrict__ qkv, const u16* __restrict__ vt, u16* __restrict__ att)
{
  __shared__ u16 Ks[2][64 * 64];
  __shared__ u16 Vs[2][64 * 64];
  const int tid = threadIdx.x;
  const int lane = tid & 63;
  const int w = tid >> 6;
  const int l31 = lane & 31;
  const int hi = lane >> 5;

  const int blk = blockIdx.x;
  const int qt = (Tn / 128 - 1) - (blk >> 6);   // heavy q-tiles dispatched first
  const int bh = blk & 63;
  const int b = bh >> 4;
  const int h = bh & 15;
  const int q0w = qt * 128 + w * 32;
  const int rowbase = b * Tn;
  const int koff = Cn + h * Dn;
  const size_t vbase = (size_t)bh * Dn * Tn;
  const int nt = 2 * qt + 2;                    // 64-wide k-tiles staged by block
  const int ntw = 2 * qt + 1 + (w >> 1);        // tiles this wave computes

  // Q B-frags: lane owns q-row q0w+l31; frag `sub` covers d = sub*16 + hi*8 + e
  short8 qf[4];
  {
    const u16* qp = qkv + (size_t)(rowbase + q0w + l31) * (3 * Cn) + h * Dn + hi * 8;
#pragma unroll
    for (int sub = 0; sub < 4; ++sub) qf[sub] = *(const short8*)(qp + sub * 16);
  }

  float m_r = -1e30f, l_r = 0.f;
  f32x16 oacc[2] = {};

#define STAGE(buf, t_)                                                            \
  {                                                                               \
    const int kt_ = (t_) * 64;                                                    \
    _Pragma("unroll")                                                             \
    for (int it = 0; it < 2; ++it) {                                              \
      int c = it * 256 + tid;                                                     \
      int row = c >> 3;                                                           \
      int cs = (c & 7) ^ (row & 7);                                               \
      const u16* gk = qkv + (size_t)(rowbase + kt_ + row) * (3 * Cn) + koff + cs * 8; \
      __builtin_amdgcn_global_load_lds((const AS1 void*)gk, (AS3 void*)(&Ks[buf][c * 8]), 16, 0, 0); \
      const u16* gv = vt + vbase + (size_t)row * Tn + kt_ + cs * 8;               \
      __builtin_amdgcn_global_load_lds((const AS1 void*)gv, (AS3 void*)(&Vs[buf][c * 8]), 16, 0, 0); \
    }                                                                             \
  }

  STAGE(0, 0);
  __syncthreads();

  for (int t = 0; t < nt; ++t) {
    const int cur = t & 1;
    if (t + 1 < nt) STAGE(cur ^ 1, t + 1);      // prefetch overlaps compute
    if (t < ntw) {
      const int kt = t * 64;
      const u16* Kb = Ks[cur];
      const u16* Vb = Vs[cur];

      // ---- S^T = K·Q^T : 2 key-blocks of 32, contract D via 4 sub-mfma ----
      f32x16 s0 = {}, s1 = {};
#pragma unroll
      for (int sub = 0; sub < 4; ++sub) {
        const int ch = sub * 2 + hi;
        const int r0 = l31;
        short8 kf0 = *(const short8*)(Kb + r0 * 64 + ((ch ^ (r0 & 7)) << 3));
        s0 = __builtin_amdgcn_mfma_f32_32x32x16_bf16(kf0, qf[sub], s0, 0, 0, 0);
        const int r1 = 32 + l31;
        short8 kf1 = *(const short8*)(Kb + r1 * 64 + ((ch ^ (r1 & 7)) << 3));
        s1 = __builtin_amdgcn_mfma_f32_32x32x16_bf16(kf1, qf[sub], s1, 0, 0, 0);
      }

      // ---- causal mask (boundary tiles only); k = kt + kblk*32 + crow(r,hi) ----
      if (kt + 63 > q0w) {
        const int qa = q0w + l31;
#pragma unroll
        for (int r = 0; r < 16; ++r) {
          const int k0 = kt + ((r & 3) + 8 * (r >> 2)) + 4 * hi;
          if (k0 > qa) s0[r] = -1e30f;
          if (k0 + 32 > qa) s1[r] = -1e30f;
        }
      }

      // ---- in-lane softmax over 32 regs + 1 cross-pair shfl ----
      float mx = s0[0];
#pragma unroll
      for (int r = 1; r < 16; ++r) mx = fmaxf(mx, s0[r]);
#pragma unroll
      for (int r = 0; r < 16; ++r) mx = fmaxf(mx, s1[r]);
      mx = fmaxf(mx, __shfl_xor(mx, 32));

      if (__any(mx > m_r + 8.f)) {              // defer-max (THR=8, log2 domain)
        const float mnew = fmaxf(m_r, mx);
        const float a = __builtin_amdgcn_exp2f(m_r - mnew);
        m_r = mnew;
        l_r *= a;
#pragma unroll
        for (int r = 0; r < 16; ++r) { oacc[0][r] *= a; oacc[1][r] *= a; }
      }

      float ps = 0.f;
#pragma unroll
      for (int r = 0; r < 16; ++r) {
        s0[r] = __builtin_amdgcn_exp2f(s0[r] - m_r); ps += s0[r];
        s1[r] = __builtin_amdgcn_exp2f(s1[r] - m_r); ps += s1[r];
      }
      ps += __shfl_xor(ps, 32);
      l_r += ps;

      // ---- P -> bf16 B-frags in-register (cvt_pk + permlane32_swap) ----
      short8 pfr[4];
#pragma unroll
      for (int ks = 0; ks < 4; ++ks) {
        const f32x16& sv = (ks < 2) ? s0 : s1;
        const int base = (ks & 1) * 8;
        unsigned a0 = cvtpk_bf16(sv[base + 0], sv[base + 1]);
        unsigned a1 = cvtpk_bf16(sv[base + 2], sv[base + 3]);
        unsigned b0 = cvtpk_bf16(sv[base + 4], sv[base + 5]);
        unsigned b1 = cvtpk_bf16(sv[base + 6], sv[base + 7]);
        uint2v s_0 = __builtin_amdgcn_permlane32_swap(a0, b0, false, false);
        uint2v s_1 = __builtin_amdgcn_permlane32_swap(a1, b1, false, false);
        union { u32x4 u; short8 s; } cvt;
        cvt.u = (u32x4){s_0.x, s_1.x, s_0.y, s_1.y};
        pfr[ks] = cvt.s;
      }

      // ---- O^T += V^T·P^T : 2 d-blocks x 4 key-sub-mfma ----
#pragma unroll
      for (int j = 0; j < 2; ++j) {
        const int rv = j * 32 + l31;
        const int rsw = (rv & 7) << 3;
#pragma unroll
        for (int ks = 0; ks < 4; ++ks) {
          short8 vf = *(const short8*)(Vb + rv * 64 + (((ks * 2 + hi) << 3) ^ rsw));
          oacc[j] = __builtin_amdgcn_mfma_f32_32x32x16_bf16(vf, pfr[ks], oacc[j], 0, 0, 0);
        }
      }
    }
    __syncthreads();   // drains prefetch (vmcnt) + all waves done with `cur`
  }

  // ---- epilogue: O^T lane-local; d = j*32 + 8*(r>>2) + (r&3) + 4*hi ----
  {
    const float inv = __builtin_amdgcn_rcpf(l_r);
    u16* orow = att + (size_t)(rowbase + q0w + l31) * Cn + h * Dn + hi * 4;
#pragma unroll
    for (int j = 0; j < 2; ++j)
#pragma unroll
      for (int g = 0; g < 4; ++g) {
        ushort4 o;
#pragma unroll
        for (int c = 0; c < 4; ++c) o[c] = f2bf(oacc[j][g * 4 + c] * inv);
        *(ushort4*)(orow + j * 32 + g * 8) = o;
      }
  }
#undef STAGE
}

extern "C" void kernel_launch(void* const* d_in, const int* in_sizes, int n_in,
                              void* d_out, int out_size, void* d_ws, size_t ws_size,
                              hipStream_t stream) {
  const float* x      = (const float*)d_in[0];   // [B,T,C]
  const float* w_qkv  = (const float*)d_in[1];   // [3C,C]
  const float* b_qkv  = (const float*)d_in[2];   // [3C]
  const float* w_proj = (const float*)d_in[3];   // [C,C]
  const float* b_proj = (const float*)d_in[4];   // [C]
  float* out = (float*)d_out;                    // [B,T,C]

  char* ws = (char*)d_ws;
  u16* x_bf     = (u16*)(ws);                         // 16.78 MB (reused as vt)
  u16* wqkv_bf  = (u16*)(ws + 16777216);              //  6.29 MB
  u16* wproj_bf = (u16*)(ws + 16777216 + 6291456);    //  2.10 MB
  u16* qkv      = (u16*)(ws + 25165824);              // 50.33 MB
  u16* att      = (u16*)(ws + 75497472);              // 16.78 MB
  u16* vt       = x_bf;   // x_bf dead after QKV GEMM; reuse for V^T [B,H,D,T]

  const int M = Bn * Tn;  // 8192

  cast_f32_to_bf16<<<(M * Cn / 4 + 255) / 256, 256, 0, stream>>>(x, x_bf, M * Cn / 4);
  cast_f32_to_bf16<<<(3 * Cn * Cn / 4 + 255) / 256, 256, 0, stream>>>(w_qkv, wqkv_bf, 3 * Cn * Cn / 4);
  cast_f32_to_bf16<<<(Cn * Cn / 4 + 255) / 256, 256, 0, stream>>>(w_proj, wproj_bf, Cn * Cn / 4);

  // qkv = x @ w_qkv^T + b_qkv; Q region (cols < 1024) pre-scaled by SCL*log2e
  gemm_nt<u16><<<dim3(3 * Cn / 128, M / 128), 256, 0, stream>>>(
      x_bf, wqkv_bf, b_qkv, qkv, M, 3 * Cn, Cn, Cn, SCL_LOG2E);

  // V^T into vt[B,H,D,T]  (overwrites x_bf, now dead)
  transpose_v<<<Bn * Hn * (Tn / 64), 256, 0, stream>>>(qkv, vt);

  // causal flash attention -> att [8192, 1024] bf16
  attn_kernel<<<Bn * Hn * (Tn / 128), 256, 0, stream>>>(qkv, vt, att);

  // out = att @ w_proj^T + b_proj   [8192, 1024] f32
  gemm_nt<float><<<dim3(Cn / 128, M / 128), 256, 0, stream>>>(
      att, wproj_bf, b_proj, out, M, Cn, Cn, 0, 1.0f);
}

// Round 6
// 177.683 us; speedup vs baseline: 3.2047x; 1.0432x over previous
//
#include <hip/hip_runtime.h>

typedef unsigned short u16;
typedef __attribute__((ext_vector_type(8))) short short8;
typedef __attribute__((ext_vector_type(4))) float f32x4;
typedef __attribute__((ext_vector_type(16))) float f32x16;
typedef __attribute__((ext_vector_type(2))) unsigned uint2v;
typedef __attribute__((ext_vector_type(4))) unsigned u32x4;

#define AS1 __attribute__((address_space(1)))
#define AS3 __attribute__((address_space(3)))

// Problem constants
constexpr int Bn = 4, Tn = 2048, Cn = 1024, Hn = 16, Dn = 64;
constexpr float SCL_LOG2E = 0.125f * 1.44269504088896f; // D^-0.5 folded into exp2 domain

__device__ __forceinline__ u16 f2bf(float f) {
  union { float f; unsigned u; } v; v.f = f;
  unsigned r = v.u + 0x7FFFu + ((v.u >> 16) & 1u);
  return (u16)(r >> 16);
}

__device__ __forceinline__ unsigned cvtpk_bf16(float a, float b) {
  unsigned r;
  asm("v_cvt_pk_bf16_f32 %0, %1, %2" : "=v"(r) : "v"(a), "v"(b));
  return r;
}

__global__ void cast_f32_to_bf16(const float* __restrict__ in, u16* __restrict__ out, int n4) {
  int i = blockIdx.x * 256 + threadIdx.x;
  if (i >= n4) return;
  float4 v = ((const float4*)in)[i];
  ushort4 o;
  o.x = f2bf(v.x); o.y = f2bf(v.y); o.z = f2bf(v.z); o.w = f2bf(v.w);
  ((ushort4*)out)[i] = o;
}

__device__ __forceinline__ void store_out(u16* p, float v) { *p = f2bf(v); }
__device__ __forceinline__ void store_out(float* p, float v) { *p = v; }

// ---------------------------------------------------------------------------
// 8-phase GEMM (T2 swizzle + T3/T4 counted vmcnt + T5 setprio + T1 XCD remap).
// C[m,n] = (sum_k A[m,k]*B[n,k] + bias[n]) * (n < qcols ? qscale : 1)
// Block: 512 threads = 8 waves (2M x 4N). BK=64. 4 phases per K-tile:
//   p0: read A-low+B-low frags | stage t+1 h1 | bar | MFMA(0,0) | bar
//   p1: read B-high            | stage t+1 h2 | bar | MFMA(0,1) | bar
//   p2: read A-high            | stage t+1 h3 | bar | MFMA(1,1) | bar
//   p3: (no reads)             | stage t+2 h0 | bar | MFMA(1,0) | vmcnt(2) | bar
// Half-tiles (128 rows x 64 cols) staged via global_load_lds, source
// chunk-XOR-swizzled (cs = cc ^ (row&7)) so ds_read_b128 frags are conflict-free.
// Steady-state: 1 half-tile (2 loads) always in flight; vmcnt never drains to 0
// except at the final boundary.
// ---------------------------------------------------------------------------
template <int BM, int BN, typename OT>
__global__ __launch_bounds__(512) void gemm8(
    const u16* __restrict__ A, const u16* __restrict__ Bm,
    const float* __restrict__ bias, OT* __restrict__ C,
    int M, int N, int K, int nbn, int qcols, float qscale)
{
  constexpr int NHA = BM / 128, NHB = BN / 128, NH = NHA + NHB;
  constexpr int MR = BM / 32;   // per-wave M frags ((BM/2)/16)
  constexpr int NR = BN / 64;   // per-wave N frags ((BN/4)/16)
  __shared__ u16 As[2][BM * 64];
  __shared__ u16 Bs[2][BN * 64];

  const int tid = threadIdx.x;
  const int lane = tid & 63;
  const int w = tid >> 6;
  const int wm = w >> 2, wn = w & 3;
  const int l15 = lane & 15, lg = lane >> 4;

  // XCD-bijective block remap (nwg % 8 == 0 for both instantiations)
  const int nwg = gridDim.x;
  const int wg = (blockIdx.x & 7) * (nwg >> 3) + (blockIdx.x >> 3);
  const int m0 = (wg / nbn) * BM;
  const int n0 = (wg % nbn) * BN;
  const int NT = K >> 6;

  const int wrow = wm * (BM / 2);
  const int wcol = wn * (BN / 4);

  f32x4 acc[MR][NR] = {};

  auto stage_half = [&](int tt, int h) {
    if (tt >= NT) return;
    const int bu = tt & 1;
#pragma unroll
    for (int it = 0; it < 2; ++it) {
      const int c = it * 512 + tid;
      const int row = c >> 3;
      const int cs = (c & 7) ^ (row & 7);
      if (h < NHA) {
        const u16* g = A + (size_t)(m0 + h * 128 + row) * K + tt * 64 + cs * 8;
        __builtin_amdgcn_global_load_lds((const AS1 void*)g,
            (AS3 void*)(&As[bu][(h * 128 + row) * 64 + (c & 7) * 8]), 16, 0, 0);
      } else {
        const int rb = (h - NHA) * 128 + row;
        const u16* g = Bm + (size_t)(n0 + rb) * K + tt * 64 + cs * 8;
        __builtin_amdgcn_global_load_lds((const AS1 void*)g,
            (AS3 void*)(&Bs[bu][rb * 64 + (c & 7) * 8]), 16, 0, 0);
      }
    }
  };

  auto readA = [&](int bu, int mh, short8 (*a)[2]) {
#pragma unroll
    for (int i = 0; i < MR / 2; ++i)
#pragma unroll
      for (int ks = 0; ks < 2; ++ks) {
        const int ra = wrow + (mh * (MR / 2) + i) * 16 + l15;
        a[i][ks] = *(const short8*)(&As[bu][ra * 64 + (((ks * 4 + lg) ^ (ra & 7)) << 3)]);
      }
  };
  auto readB = [&](int bu, int nh, short8 (*b)[2]) {
#pragma unroll
    for (int j = 0; j < NR / 2; ++j)
#pragma unroll
      for (int ks = 0; ks < 2; ++ks) {
        const int rb = wcol + (nh * (NR / 2) + j) * 16 + l15;
        b[j][ks] = *(const short8*)(&Bs[bu][rb * 64 + (((ks * 4 + lg) ^ (rb & 7)) << 3)]);
      }
  };
  auto mmaq = [&](int mh, int nh, short8 (*a)[2], short8 (*b)[2]) {
    __builtin_amdgcn_s_setprio(1);
#pragma unroll
    for (int i = 0; i < MR / 2; ++i)
#pragma unroll
      for (int j = 0; j < NR / 2; ++j)
#pragma unroll
        for (int ks = 0; ks < 2; ++ks)
          acc[mh * (MR / 2) + i][nh * (NR / 2) + j] =
              __builtin_amdgcn_mfma_f32_16x16x32_bf16(
                  a[i][ks], b[j][ks], acc[mh * (MR / 2) + i][nh * (NR / 2) + j], 0, 0, 0);
    __builtin_amdgcn_s_setprio(0);
  };

  // ---- prologue: tile0 all halves + tile1 h0; tile0 landed, 2 loads in flight
#pragma unroll
  for (int h = 0; h < NH; ++h) stage_half(0, h);
  stage_half(1, 0);
  asm volatile("s_waitcnt vmcnt(2)" ::: "memory");
  __builtin_amdgcn_sched_barrier(0);
  __builtin_amdgcn_s_barrier();

  for (int t = 0; t < NT; ++t) {
    const int bu = t & 1;
    short8 a0[MR / 2][2], a1[MR / 2][2], b0[NR / 2][2], b1[NR / 2][2];
    // ---- phase 0 ----
    readA(bu, 0, a0);
    readB(bu, 0, b0);
    stage_half(t + 1, 1);
    __builtin_amdgcn_s_barrier();
    mmaq(0, 0, a0, b0);
    __builtin_amdgcn_s_barrier();
    // ---- phase 1 ----
    readB(bu, 1, b1);
    stage_half(t + 1, 2);
    __builtin_amdgcn_s_barrier();
    mmaq(0, 1, a0, b1);
    __builtin_amdgcn_s_barrier();
    // ---- phase 2 ----
    readA(bu, 1, a1);
    if constexpr (NH > 3) stage_half(t + 1, 3);
    __builtin_amdgcn_s_barrier();
    mmaq(1, 1, a1, b1);
    __builtin_amdgcn_s_barrier();
    // ---- phase 3 (no ds_reads; buffer bu's reads ended at phase-2 barrier) ----
    stage_half(t + 2, 0);
    __builtin_amdgcn_s_barrier();
    mmaq(1, 0, a1, b0);
    if (t < NT - 1) {
      if (t + 2 < NT) asm volatile("s_waitcnt vmcnt(2)" ::: "memory");
      else            asm volatile("s_waitcnt vmcnt(0)" ::: "memory");
      __builtin_amdgcn_sched_barrier(0);
    }
    __builtin_amdgcn_s_barrier();
  }

  // ---- epilogue ----
#pragma unroll
  for (int i = 0; i < MR; ++i) {
    const int rowg = m0 + wrow + i * 16 + lg * 4;
#pragma unroll
    for (int j = 0; j < NR; ++j) {
      const int colg = n0 + wcol + j * 16 + l15;
      const float sc = (colg < qcols) ? qscale : 1.0f;
      const float bv = bias[colg];
#pragma unroll
      for (int r = 0; r < 4; ++r)
        store_out(C + (size_t)(rowg + r) * N + colg, (acc[i][j][r] + bv) * sc);
    }
  }
}

// Transpose V from qkv[B*T][3C] (v at +2C, per-head D=64) into vt[B,H,D,T].
__global__ __launch_bounds__(256) void transpose_v(
    const u16* __restrict__ qkv, u16* __restrict__ vt)
{
  __shared__ u16 tile[64][72];
  const int bh = blockIdx.x >> 5;
  const int tt = blockIdx.x & 31;
  const int b = bh >> 4;
  const int h = bh & 15;
  const int tid = threadIdx.x;
  const int trow = tid >> 2;
  const int dseg = tid & 3;

  const u16* src = qkv + (size_t)(b * Tn + tt * 64 + trow) * (3 * Cn) + 2 * Cn + h * Dn + dseg * 16;
  short8 v0 = *(const short8*)src;
  short8 v1 = *(const short8*)(src + 8);
#pragma unroll
  for (int e = 0; e < 8; ++e) {
    tile[dseg * 16 + e][trow] = (u16)v0[e];
    tile[dseg * 16 + 8 + e][trow] = (u16)v1[e];
  }
  __syncthreads();

  const int drow = tid >> 2;
  const int tseg = tid & 3;
  u16* dst = vt + (size_t)(bh * Dn + drow) * Tn + tt * 64 + tseg * 16;
  *(short8*)dst = *(const short8*)&tile[drow][tseg * 16];
  *(short8*)(dst + 8) = *(const short8*)&tile[drow][tseg * 16 + 8];
}

// Causal flash attention, swapped-operand structure (m214 style):
//   S^T = mfma_32x32x16(A=K, B=Q)  -> lane owns full q-row (q = lane&31)
//   softmax fully in-lane; P -> bf16 B-frags via cvt_pk + permlane32_swap (T12)
//   O^T = mfma(A=V^T-frag, B=P-frag) -> O, m, l all lane-local
__global__ __launch_bounds__(256) void attn_kernel(
    const u16* __restrict__ qkv, const u16* __restrict__ vt, u16* __restrict__ att)
{
  __shared__ u16 Ks[2][64 * 64];
  __shared__ u16 Vs[2][64 * 64];
  const int tid = threadIdx.x;
  const int lane = tid & 63;
  const int w = tid >> 6;
  const int l31 = lane & 31;
  const int hi = lane >> 5;

  const int blk = blockIdx.x;
  const int qt = (Tn / 128 - 1) - (blk >> 6);   // heavy q-tiles dispatched first
  const int bh = blk & 63;
  const int b = bh >> 4;
  const int h = bh & 15;
  const int q0w = qt * 128 + w * 32;
  const int rowbase = b * Tn;
  const int koff = Cn + h * Dn;
  const size_t vbase = (size_t)bh * Dn * Tn;
  const int nt = 2 * qt + 2;
  const int ntw = 2 * qt + 1 + (w >> 1);

  short8 qf[4];
  {
    const u16* qp = qkv + (size_t)(rowbase + q0w + l31) * (3 * Cn) + h * Dn + hi * 8;
#pragma unroll
    for (int sub = 0; sub < 4; ++sub) qf[sub] = *(const short8*)(qp + sub * 16);
  }

  float m_r = -1e30f, l_r = 0.f;
  f32x16 oacc[2] = {};

#define STAGE(buf, t_)                                                            \
  {                                                                               \
    const int kt_ = (t_) * 64;                                                    \
    _Pragma("unroll")                                                             \
    for (int it = 0; it < 2; ++it) {                                              \
      int c = it * 256 + tid;                                                     \
      int row = c >> 3;                                                           \
      int cs = (c & 7) ^ (row & 7);                                               \
      const u16* gk = qkv + (size_t)(rowbase + kt_ + row) * (3 * Cn) + koff + cs * 8; \
      __builtin_amdgcn_global_load_lds((const AS1 void*)gk, (AS3 void*)(&Ks[buf][c * 8]), 16, 0, 0); \
      const u16* gv = vt + vbase + (size_t)row * Tn + kt_ + cs * 8;               \
      __builtin_amdgcn_global_load_lds((const AS1 void*)gv, (AS3 void*)(&Vs[buf][c * 8]), 16, 0, 0); \
    }                                                                             \
  }

  STAGE(0, 0);
  __syncthreads();

  for (int t = 0; t < nt; ++t) {
    const int cur = t & 1;
    if (t + 1 < nt) STAGE(cur ^ 1, t + 1);
    if (t < ntw) {
      const int kt = t * 64;
      const u16* Kb = Ks[cur];
      const u16* Vb = Vs[cur];

      f32x16 s0 = {}, s1 = {};
#pragma unroll
      for (int sub = 0; sub < 4; ++sub) {
        const int ch = sub * 2 + hi;
        const int r0 = l31;
        short8 kf0 = *(const short8*)(Kb + r0 * 64 + ((ch ^ (r0 & 7)) << 3));
        s0 = __builtin_amdgcn_mfma_f32_32x32x16_bf16(kf0, qf[sub], s0, 0, 0, 0);
        const int r1 = 32 + l31;
        short8 kf1 = *(const short8*)(Kb + r1 * 64 + ((ch ^ (r1 & 7)) << 3));
        s1 = __builtin_amdgcn_mfma_f32_32x32x16_bf16(kf1, qf[sub], s1, 0, 0, 0);
      }

      if (kt + 63 > q0w) {
        const int qa = q0w + l31;
#pragma unroll
        for (int r = 0; r < 16; ++r) {
          const int k0 = kt + ((r & 3) + 8 * (r >> 2)) + 4 * hi;
          if (k0 > qa) s0[r] = -1e30f;
          if (k0 + 32 > qa) s1[r] = -1e30f;
        }
      }

      float mx = s0[0];
#pragma unroll
      for (int r = 1; r < 16; ++r) mx = fmaxf(mx, s0[r]);
#pragma unroll
      for (int r = 0; r < 16; ++r) mx = fmaxf(mx, s1[r]);
      mx = fmaxf(mx, __shfl_xor(mx, 32));

      if (__any(mx > m_r + 8.f)) {              // defer-max (THR=8, log2 domain)
        const float mnew = fmaxf(m_r, mx);
        const float a = __builtin_amdgcn_exp2f(m_r - mnew);
        m_r = mnew;
        l_r *= a;
#pragma unroll
        for (int r = 0; r < 16; ++r) { oacc[0][r] *= a; oacc[1][r] *= a; }
      }

      float ps = 0.f;
#pragma unroll
      for (int r = 0; r < 16; ++r) {
        s0[r] = __builtin_amdgcn_exp2f(s0[r] - m_r); ps += s0[r];
        s1[r] = __builtin_amdgcn_exp2f(s1[r] - m_r); ps += s1[r];
      }
      ps += __shfl_xor(ps, 32);
      l_r += ps;

      short8 pfr[4];
#pragma unroll
      for (int ks = 0; ks < 4; ++ks) {
        const f32x16& sv = (ks < 2) ? s0 : s1;
        const int base = (ks & 1) * 8;
        unsigned a0 = cvtpk_bf16(sv[base + 0], sv[base + 1]);
        unsigned a1 = cvtpk_bf16(sv[base + 2], sv[base + 3]);
        unsigned b0 = cvtpk_bf16(sv[base + 4], sv[base + 5]);
        unsigned b1 = cvtpk_bf16(sv[base + 6], sv[base + 7]);
        uint2v s_0 = __builtin_amdgcn_permlane32_swap(a0, b0, false, false);
        uint2v s_1 = __builtin_amdgcn_permlane32_swap(a1, b1, false, false);
        union { u32x4 u; short8 s; } cvt;
        cvt.u = (u32x4){s_0.x, s_1.x, s_0.y, s_1.y};
        pfr[ks] = cvt.s;
      }

#pragma unroll
      for (int j = 0; j < 2; ++j) {
        const int rv = j * 32 + l31;
        const int rsw = (rv & 7) << 3;
#pragma unroll
        for (int ks = 0; ks < 4; ++ks) {
          short8 vf = *(const short8*)(Vb + rv * 64 + (((ks * 2 + hi) << 3) ^ rsw));
          oacc[j] = __builtin_amdgcn_mfma_f32_32x32x16_bf16(vf, pfr[ks], oacc[j], 0, 0, 0);
        }
      }
    }
    __syncthreads();
  }

  {
    const float inv = __builtin_amdgcn_rcpf(l_r);
    u16* orow = att + (size_t)(rowbase + q0w + l31) * Cn + h * Dn + hi * 4;
#pragma unroll
    for (int j = 0; j < 2; ++j)
#pragma unroll
      for (int g = 0; g < 4; ++g) {
        ushort4 o;
#pragma unroll
        for (int c = 0; c < 4; ++c) o[c] = f2bf(oacc[j][g * 4 + c] * inv);
        *(ushort4*)(orow + j * 32 + g * 8) = o;
      }
  }
#undef STAGE
}

extern "C" void kernel_launch(void* const* d_in, const int* in_sizes, int n_in,
                              void* d_out, int out_size, void* d_ws, size_t ws_size,
                              hipStream_t stream) {
  const float* x      = (const float*)d_in[0];   // [B,T,C]
  const float* w_qkv  = (const float*)d_in[1];   // [3C,C]
  const float* b_qkv  = (const float*)d_in[2];   // [3C]
  const float* w_proj = (const float*)d_in[3];   // [C,C]
  const float* b_proj = (const float*)d_in[4];   // [C]
  float* out = (float*)d_out;                    // [B,T,C]

  char* ws = (char*)d_ws;
  u16* x_bf     = (u16*)(ws);                         // 16.78 MB (reused as vt)
  u16* wqkv_bf  = (u16*)(ws + 16777216);              //  6.29 MB
  u16* wproj_bf = (u16*)(ws + 16777216 + 6291456);    //  2.10 MB
  u16* qkv      = (u16*)(ws + 25165824);              // 50.33 MB
  u16* att      = (u16*)(ws + 75497472);              // 16.78 MB
  u16* vt       = x_bf;   // x_bf dead after QKV GEMM; reuse for V^T [B,H,D,T]

  const int M = Bn * Tn;  // 8192

  cast_f32_to_bf16<<<(M * Cn / 4 + 255) / 256, 256, 0, stream>>>(x, x_bf, M * Cn / 4);
  cast_f32_to_bf16<<<(3 * Cn * Cn / 4 + 255) / 256, 256, 0, stream>>>(w_qkv, wqkv_bf, 3 * Cn * Cn / 4);
  cast_f32_to_bf16<<<(Cn * Cn / 4 + 255) / 256, 256, 0, stream>>>(w_proj, wproj_bf, Cn * Cn / 4);

  // qkv = x @ w_qkv^T + b_qkv; Q region (cols < 1024) pre-scaled by SCL*log2e
  // grid 32x12 = 384 blocks (%8==0 for XCD remap)
  gemm8<256, 256, u16><<<384, 512, 0, stream>>>(
      x_bf, wqkv_bf, b_qkv, qkv, M, 3 * Cn, Cn, 12, Cn, SCL_LOG2E);

  // V^T into vt[B,H,D,T]  (overwrites x_bf, now dead)
  transpose_v<<<Bn * Hn * (Tn / 64), 256, 0, stream>>>(qkv, vt);

  // causal flash attention -> att [8192, 1024] bf16
  attn_kernel<<<Bn * Hn * (Tn / 128), 256, 0, stream>>>(qkv, vt, att);

  // out = att @ w_proj^T + b_proj; grid 64x4 = 256 blocks = 1/CU
  gemm8<128, 256, float><<<256, 512, 0, stream>>>(
      att, wproj_bf, b_proj, out, M, Cn, Cn, 4, 0, 1.0f);
}